// Round 1
// baseline (698.109 us; speedup 1.0000x reference)
//
#include <hip/hip_runtime.h>

typedef unsigned short u16;
typedef __bf16 bf16x8 __attribute__((ext_vector_type(8)));
typedef float f32x4 __attribute__((ext_vector_type(4)));

#define B_   2
#define S_   2048
#define HID_ 2048
#define H_   16
#define KV_  4
#define D_   128

__device__ __forceinline__ u16 f2b(float f) {
  unsigned u = __float_as_uint(f);
  return (u16)((u + 0x7fffu + ((u >> 16) & 1u)) >> 16);  // RNE
}
__device__ __forceinline__ float b2f(u16 h) {
  return __uint_as_float(((unsigned)h) << 16);
}
__device__ __forceinline__ void cstore(float* p, float v) { *p = v; }
__device__ __forceinline__ void cstore(u16* p, float v)   { *p = f2b(v); }

// ---------------------------------------------------------------- cast x -> bf16
__global__ __launch_bounds__(256)
void cast_f2b_kernel(const float* __restrict__ in, u16* __restrict__ out, int n) {
  int i = (blockIdx.x * 256 + threadIdx.x) * 4;
  if (i + 3 < n) {
    float4 v = *(const float4*)(in + i);
    ushort4 r = make_ushort4(f2b(v.x), f2b(v.y), f2b(v.z), f2b(v.w));
    *(ushort4*)(out + i) = r;
  }
}

// ------------------------------------------- W (R x C) fp32 -> Wt (C x R) bf16
__global__ __launch_bounds__(256)
void transpose_w_kernel(const float* __restrict__ in, u16* __restrict__ out,
                        int R, int Cc) {
  __shared__ u16 t[32][33];
  const int tx = threadIdx.x, ty = threadIdx.y;
  const int c0 = blockIdx.x * 32, r0 = blockIdx.y * 32;
#pragma unroll
  for (int i = 0; i < 4; i++)
    t[ty + i * 8][tx] = f2b(in[(size_t)(r0 + ty + i * 8) * Cc + c0 + tx]);
  __syncthreads();
#pragma unroll
  for (int i = 0; i < 4; i++)
    out[(size_t)(c0 + ty + i * 8) * R + r0 + tx] = t[tx][ty + i * 8];
}

// ------------------- v (B,S,KV,D) bf16 -> Vt (B,KV,D,S) bf16  (per (b,kv) transpose)
__global__ __launch_bounds__(256)
void transpose_v_kernel(const u16* __restrict__ in, u16* __restrict__ out) {
  __shared__ u16 t[32][33];
  const int tx = threadIdx.x, ty = threadIdx.y;
  const int s0 = blockIdx.x * 32, d0 = blockIdx.y * 32;
  const int z = blockIdx.z, b = z >> 2, kv = z & 3;
#pragma unroll
  for (int i = 0; i < 4; i++)
    t[ty + i * 8][tx] =
        in[((size_t)(b * S_ + s0 + ty + i * 8) * KV_ + kv) * D_ + d0 + tx];
  __syncthreads();
#pragma unroll
  for (int i = 0; i < 4; i++)
    out[((size_t)(b * KV_ + kv) * D_ + d0 + ty + i * 8) * S_ + s0 + tx] =
        t[tx][ty + i * 8];
}

// --------------------------------- NT GEMM: A (M,K) bf16, Bt (N,K) bf16, C (M,N)
// 128x128 tile, BK=32, 4 waves (2x2), 4x4 mfma tiles/wave.
// LDS rows padded to 40 elems: 16B-aligned b128 frags, bank-uniform.
template <typename CT>
__global__ __launch_bounds__(256)
void gemm_nt(const u16* __restrict__ A, const u16* __restrict__ Bt,
             CT* __restrict__ C, int Md, int Nd, int Kd) {
  __shared__ u16 As[128 * 40];
  __shared__ u16 Bs[128 * 40];
  const int tid = threadIdx.x;
  const int lane = tid & 63;
  const int wave = tid >> 6;
  const int wm = wave >> 1, wn = wave & 1;
  const int li = lane & 15, quad = lane >> 4;
  const int m0 = blockIdx.y * 128;
  const int n0 = blockIdx.x * 128;

  f32x4 acc[4][4];
#pragma unroll
  for (int i = 0; i < 4; i++)
#pragma unroll
    for (int j = 0; j < 4; j++) acc[i][j] = (f32x4){0.f, 0.f, 0.f, 0.f};

  const int srow = tid >> 1;
  const int scol = (tid & 1) * 16;
  const u16* Agp = A + (size_t)(m0 + srow) * Kd + scol;
  const u16* Bgp = Bt + (size_t)(n0 + srow) * Kd + scol;
  u16* Asw = &As[srow * 40 + scol];
  u16* Bsw = &Bs[srow * 40 + scol];

  for (int k0 = 0; k0 < Kd; k0 += 32) {
    uint4 a0 = *(const uint4*)(Agp + k0);
    uint4 a1 = *(const uint4*)(Agp + k0 + 8);
    uint4 b0 = *(const uint4*)(Bgp + k0);
    uint4 b1 = *(const uint4*)(Bgp + k0 + 8);
    *(uint4*)(Asw) = a0;
    *(uint4*)(Asw + 8) = a1;
    *(uint4*)(Bsw) = b0;
    *(uint4*)(Bsw + 8) = b1;
    __syncthreads();
    bf16x8 af[4], bfr[4];
#pragma unroll
    for (int mt = 0; mt < 4; mt++)
      af[mt] = *(const bf16x8*)&As[(wm * 64 + mt * 16 + li) * 40 + quad * 8];
#pragma unroll
    for (int nt = 0; nt < 4; nt++)
      bfr[nt] = *(const bf16x8*)&Bs[(wn * 64 + nt * 16 + li) * 40 + quad * 8];
#pragma unroll
    for (int mt = 0; mt < 4; mt++)
#pragma unroll
      for (int nt = 0; nt < 4; nt++)
        acc[mt][nt] = __builtin_amdgcn_mfma_f32_16x16x32_bf16(
            af[mt], bfr[nt], acc[mt][nt], 0, 0, 0);
    __syncthreads();
  }
#pragma unroll
  for (int mt = 0; mt < 4; mt++) {
    const int row = m0 + wm * 64 + mt * 16 + quad * 4;
#pragma unroll
    for (int nt = 0; nt < 4; nt++) {
      const int col = n0 + wn * 64 + nt * 16 + li;
#pragma unroll
      for (int r = 0; r < 4; r++)
        cstore(&C[(size_t)(row + r) * Nd + col], acc[mt][nt][r]);
    }
  }
}

// ------------------------ fused RMSNorm (w+1) + RoPE; warp per (token, head)
// in: (B*S tokens) x [tok_stride], head at head_stride, first D elems used.
// out: (B, n_heads, S, D) bf16.
__global__ __launch_bounds__(256)
void rmsrope_kernel(const u16* __restrict__ in, const float* __restrict__ w,
                    u16* __restrict__ out, int n_heads, int tok_stride,
                    int head_stride) {
  const int warp = (blockIdx.x << 2) + (threadIdx.x >> 6);
  const int lane = threadIdx.x & 63;
  const int h = warp % n_heads;
  const int tok = warp / n_heads;
  const int s = tok & (S_ - 1);
  const int b = tok >> 11;
  const u16* src = in + (size_t)tok * tok_stride + (size_t)h * head_stride;
  float x1 = b2f(src[lane]);
  float x2 = b2f(src[lane + 64]);
  float ss = x1 * x1 + x2 * x2;
#pragma unroll
  for (int off = 1; off < 64; off <<= 1) ss += __shfl_xor(ss, off);
  const float inv = rsqrtf(ss * (1.0f / 128.0f) + 1e-6f);
  x1 *= inv * (w[lane] + 1.0f);
  x2 *= inv * (w[lane + 64] + 1.0f);
  // inv_freq = 1e6^(-lane/64) ; cos/sin index d and d+64 share freq index lane
  const float invf = exp2f((float)lane * (-19.931568569324174f / 64.0f));
  const float ang = (float)s * invf;
  float sn, c;
  sincosf(ang, &sn, &c);
  const size_t ob = (((size_t)b * n_heads + h) * S_ + s) * D_;
  out[ob + lane]      = f2b(x1 * c - x2 * sn);
  out[ob + lane + 64] = f2b(x2 * c + x1 * sn);
}

// --------------------------- flash attention, GQA causal, MFMA 16x16x32 bf16
// grid (S/64, B*H); 4 waves x 16 q-rows; Bc=32 key tile.
__global__ __launch_bounds__(256)
void attn_kernel(const u16* __restrict__ Q, const u16* __restrict__ Kr,
                 const u16* __restrict__ Vt, u16* __restrict__ O) {
  __shared__ u16 Ks[32 * 136];    // keys x D (pad 8)
  __shared__ u16 Vs[128 * 40];    // d x keys (pad 8)
  __shared__ u16 Ps[4 * 16 * 40]; // per-wave P
  __shared__ u16 Osm[64 * 136];   // output staging

  const int tid = threadIdx.x;
  const int lane = tid & 63;
  const int wave = tid >> 6;
  const int li = lane & 15;
  const int quad = lane >> 4;

  const int bh = blockIdx.y;
  const int b = bh >> 4;
  const int h = bh & 15;
  const int kv = h >> 2;  // G=4
  const int qb = blockIdx.x * 64;

  const u16* Qb = Q + (size_t)bh * S_ * D_;
  const u16* Kb = Kr + ((size_t)b * KV_ + kv) * S_ * D_;
  const u16* Vb = Vt + ((size_t)b * KV_ + kv) * D_ * S_;

  bf16x8 qf[4];
  {
    const u16* qp = Qb + (size_t)(qb + wave * 16 + li) * D_ + quad * 8;
#pragma unroll
    for (int dc = 0; dc < 4; dc++) qf[dc] = *(const bf16x8*)(qp + dc * 32);
  }

  float m_r[4], l_r[4];
  f32x4 oacc[8];
#pragma unroll
  for (int r = 0; r < 4; r++) { m_r[r] = -1e30f; l_r[r] = 0.0f; }
#pragma unroll
  for (int i = 0; i < 8; i++) oacc[i] = (f32x4){0.f, 0.f, 0.f, 0.f};

  const int ntile = (qb >> 5) + 2;          // causal: keys <= qb+63
  const int qrow0 = qb + wave * 16 + quad * 4;

  for (int jt = 0; jt < ntile; jt++) {
    const int j0 = jt * 32;
    __syncthreads();
    {  // stage K tile (32 x 128)
      int r = tid >> 3, c = (tid & 7) * 16;
      const u16* src = Kb + (size_t)(j0 + r) * D_ + c;
      *(uint4*)&Ks[r * 136 + c]     = *(const uint4*)(src);
      *(uint4*)&Ks[r * 136 + c + 8] = *(const uint4*)(src + 8);
    }
    {  // stage V^T tile (128 x 32)
      int r = tid >> 1, c = (tid & 1) * 16;
      const u16* src = Vb + (size_t)r * S_ + j0 + c;
      *(uint4*)&Vs[r * 40 + c]     = *(const uint4*)(src);
      *(uint4*)&Vs[r * 40 + c + 8] = *(const uint4*)(src + 8);
    }
    __syncthreads();

    f32x4 sacc[2] = {};
#pragma unroll
    for (int nt = 0; nt < 2; nt++)
#pragma unroll
      for (int dc = 0; dc < 4; dc++) {
        bf16x8 kf =
            *(const bf16x8*)&Ks[(nt * 16 + li) * 136 + dc * 32 + quad * 8];
        sacc[nt] =
            __builtin_amdgcn_mfma_f32_16x16x32_bf16(qf[dc], kf, sacc[nt], 0, 0, 0);
      }

    float p[2][4], mx[4];
#pragma unroll
    for (int r = 0; r < 4; r++) mx[r] = -1e30f;
#pragma unroll
    for (int nt = 0; nt < 2; nt++) {
      const int krow = j0 + nt * 16 + li;
#pragma unroll
      for (int r = 0; r < 4; r++) {
        float sv = sacc[nt][r] * 0.08838834764831845f;
        if (krow > qrow0 + r) sv = -1e30f;
        p[nt][r] = sv;
        mx[r] = fmaxf(mx[r], sv);
      }
    }
#pragma unroll
    for (int off = 1; off < 16; off <<= 1)
#pragma unroll
      for (int r = 0; r < 4; r++) mx[r] = fmaxf(mx[r], __shfl_xor(mx[r], off));

    float alpha[4];
#pragma unroll
    for (int r = 0; r < 4; r++) {
      float mn = fmaxf(m_r[r], mx[r]);
      alpha[r] = __expf(m_r[r] - mn);
      m_r[r] = mn;
    }
    float rs[4];
#pragma unroll
    for (int r = 0; r < 4; r++) {
      p[0][r] = __expf(p[0][r] - m_r[r]);
      p[1][r] = __expf(p[1][r] - m_r[r]);
      rs[r] = p[0][r] + p[1][r];
    }
#pragma unroll
    for (int off = 1; off < 16; off <<= 1)
#pragma unroll
      for (int r = 0; r < 4; r++) rs[r] += __shfl_xor(rs[r], off);
#pragma unroll
    for (int r = 0; r < 4; r++) l_r[r] = l_r[r] * alpha[r] + rs[r];
#pragma unroll
    for (int i = 0; i < 8; i++)
#pragma unroll
      for (int r = 0; r < 4; r++) oacc[i][r] *= alpha[r];

    u16* Pw = Ps + wave * 16 * 40;  // C-layout -> LDS -> A-layout
#pragma unroll
    for (int nt = 0; nt < 2; nt++)
#pragma unroll
      for (int r = 0; r < 4; r++)
        Pw[(quad * 4 + r) * 40 + nt * 16 + li] = f2b(p[nt][r]);
    __syncthreads();
    bf16x8 pf = *(const bf16x8*)&Pw[li * 40 + quad * 8];
#pragma unroll
    for (int nt = 0; nt < 8; nt++) {
      bf16x8 vf = *(const bf16x8*)&Vs[(nt * 16 + li) * 40 + quad * 8];
      oacc[nt] = __builtin_amdgcn_mfma_f32_16x16x32_bf16(pf, vf, oacc[nt], 0, 0, 0);
    }
  }

  float linv[4];
#pragma unroll
  for (int r = 0; r < 4; r++) linv[r] = 1.0f / l_r[r];
#pragma unroll
  for (int nt = 0; nt < 8; nt++)
#pragma unroll
    for (int r = 0; r < 4; r++)
      Osm[(wave * 16 + quad * 4 + r) * 136 + nt * 16 + li] =
          f2b(oacc[nt][r] * linv[r]);
  __syncthreads();
  {  // coalesced copy-out: O layout (B,S,H,D)
    int r = tid >> 2, c0 = (tid & 3) * 32;
    u16* dst = O + (((size_t)(b * S_ + qb + r) * H_) + h) * D_;
#pragma unroll
    for (int i = 0; i < 4; i++)
      *(uint4*)(dst + c0 + i * 8) = *(const uint4*)&Osm[r * 136 + c0 + i * 8];
  }
}

// ----------------------------------------------- sigmoid gate: Ag = O * sig(gate)
__global__ __launch_bounds__(256)
void gate_kernel(const u16* __restrict__ O, const u16* __restrict__ qraw,
                 u16* __restrict__ Ag, int n) {
  int i = blockIdx.x * 256 + threadIdx.x;
  if (i >= n) return;
  int d = i & 127;
  int h = (i >> 7) & 15;
  int bs = i >> 11;
  float g = b2f(qraw[((size_t)bs * 16 + h) * 256 + 128 + d]);
  float o = b2f(O[i]);
  Ag[i] = f2b(o / (1.0f + __expf(-g)));
}

extern "C" void kernel_launch(void* const* d_in, const int* in_sizes, int n_in,
                              void* d_out, int out_size, void* d_ws,
                              size_t ws_size, hipStream_t stream) {
  const float* x  = (const float*)d_in[0];
  const float* Wq = (const float*)d_in[1];
  const float* Wk = (const float*)d_in[2];
  const float* Wv = (const float*)d_in[3];
  const float* Wo = (const float*)d_in[4];
  const float* qn = (const float*)d_in[5];
  const float* kn = (const float*)d_in[6];
  float* out = (float*)d_out;
  char* ws = (char*)d_ws;

  // workspace layout (bytes); Qr aliases xb (dead after stage-1 GEMMs),
  // O aliases Wqt (dead after q-GEMM). Peak = 113,246,208 B.
  u16* xb   = (u16*)(ws + 0);          // 16.8 MB  x bf16 (4096x2048)
  u16* Wqt  = (u16*)(ws + 16777216);   // 16.8 MB  Wq^T (4096x2048)
  u16* Wkt  = (u16*)(ws + 33554432);   //  2.1 MB  Wk^T (512x2048)
  u16* Wvt  = (u16*)(ws + 35651584);   //  2.1 MB  Wv^T (512x2048)
  u16* Wot  = (u16*)(ws + 37748736);   //  8.4 MB  Wo^T (2048x2048)
  u16* qraw = (u16*)(ws + 46137344);   // 33.6 MB  q_raw (4096x4096)
  u16* kraw = (u16*)(ws + 79691776);   //  4.2 MB  k (4096x512)
  u16* vraw = (u16*)(ws + 83886080);   //  4.2 MB  v (4096x512)
  u16* Vtb  = (u16*)(ws + 88080384);   //  4.2 MB  V^T (B,KV,D,S)
  u16* Kr   = (u16*)(ws + 92274688);   //  4.2 MB  K roped (B,KV,S,D)
  u16* Ag   = (u16*)(ws + 96468992);   // 16.8 MB  gated attn (4096x2048)
  u16* Qr = xb;    // (B,H,S,D) roped Q
  u16* Ob = Wqt;   // (B,S,H,D) attention out

  cast_f2b_kernel<<<8192, 256, 0, stream>>>(x, xb, 4096 * 2048);
  transpose_w_kernel<<<dim3(128, 64), dim3(32, 8), 0, stream>>>(Wq, Wqt, 2048, 4096);
  transpose_w_kernel<<<dim3(16, 64), dim3(32, 8), 0, stream>>>(Wk, Wkt, 2048, 512);
  transpose_w_kernel<<<dim3(16, 64), dim3(32, 8), 0, stream>>>(Wv, Wvt, 2048, 512);
  transpose_w_kernel<<<dim3(64, 64), dim3(32, 8), 0, stream>>>(Wo, Wot, 2048, 2048);

  gemm_nt<u16><<<dim3(32, 32), 256, 0, stream>>>(xb, Wqt, qraw, 4096, 4096, 2048);
  gemm_nt<u16><<<dim3(4, 32), 256, 0, stream>>>(xb, Wkt, kraw, 4096, 512, 2048);
  gemm_nt<u16><<<dim3(4, 32), 256, 0, stream>>>(xb, Wvt, vraw, 4096, 512, 2048);

  rmsrope_kernel<<<16384, 256, 0, stream>>>(qraw, qn, Qr, 16, 4096, 256);
  rmsrope_kernel<<<4096, 256, 0, stream>>>(kraw, kn, Kr, 4, 512, 128);
  transpose_v_kernel<<<dim3(64, 4, 8), dim3(32, 8), 0, stream>>>(vraw, Vtb);

  attn_kernel<<<dim3(32, 32), 256, 0, stream>>>(Qr, Kr, Vtb, Ob);
  gate_kernel<<<32768, 256, 0, stream>>>(Ob, qraw, Ag, 8388608);
  gemm_nt<float><<<dim3(16, 32), 256, 0, stream>>>(Ag, Wot, out, 4096, 2048, 2048);
}

// Round 3
// 584.936 us; speedup vs baseline: 1.1935x; 1.1935x over previous
//
#include <hip/hip_runtime.h>

typedef unsigned short u16;
typedef __bf16 bf16x8 __attribute__((ext_vector_type(8)));
typedef float f32x4 __attribute__((ext_vector_type(4)));

#define B_   2
#define S_   2048
#define HID_ 2048
#define H_   16
#define KV_  4
#define D_   128

__device__ __forceinline__ u16 f2b(float f) {
  unsigned u = __float_as_uint(f);
  return (u16)((u + 0x7fffu + ((u >> 16) & 1u)) >> 16);  // RNE
}
__device__ __forceinline__ float b2f(u16 h) {
  return __uint_as_float(((unsigned)h) << 16);
}
__device__ __forceinline__ unsigned pk2(float a, float b) {
  return ((unsigned)f2b(b) << 16) | (unsigned)f2b(a);  // a low 16, b high 16
}
__device__ __forceinline__ void cstore(float* p, float v) { *p = v; }
__device__ __forceinline__ void cstore(u16* p, float v)   { *p = f2b(v); }

// async global->LDS, 16B per lane; LDS dest = wave-uniform base + lane*16
__device__ __forceinline__ void gl_lds16(const u16* g, u16* l) {
  __builtin_amdgcn_global_load_lds(
      (const __attribute__((address_space(1))) unsigned int*)g,
      (__attribute__((address_space(3))) unsigned int*)l, 16, 0, 0);
}

// ---------------------------------------------------------------- cast x -> bf16
__global__ __launch_bounds__(256)
void cast_f2b_kernel(const float* __restrict__ in, u16* __restrict__ out, int n) {
  int i = (blockIdx.x * 256 + threadIdx.x) * 4;
  if (i + 3 < n) {
    float4 v = *(const float4*)(in + i);
    uint2 r = make_uint2(pk2(v.x, v.y), pk2(v.z, v.w));
    *(uint2*)(out + i) = r;
  }
}

// ------------------------------------------- W (R x C) fp32 -> Wt (C x R) bf16
__global__ __launch_bounds__(256)
void transpose_w_kernel(const float* __restrict__ in, u16* __restrict__ out,
                        int R, int Cc) {
  __shared__ u16 t[32][33];
  const int tx = threadIdx.x, ty = threadIdx.y;
  const int c0 = blockIdx.x * 32, r0 = blockIdx.y * 32;
#pragma unroll
  for (int i = 0; i < 4; i++)
    t[ty + i * 8][tx] = f2b(in[(size_t)(r0 + ty + i * 8) * Cc + c0 + tx]);
  __syncthreads();
#pragma unroll
  for (int i = 0; i < 4; i++)
    out[(size_t)(c0 + ty + i * 8) * R + r0 + tx] = t[tx][ty + i * 8];
}

// ------------------- v (B,S,KV,D) bf16 -> Vt (B,KV,D,S) bf16
__global__ __launch_bounds__(256)
void transpose_v_kernel(const u16* __restrict__ in, u16* __restrict__ out) {
  __shared__ u16 t[32][33];
  const int tx = threadIdx.x, ty = threadIdx.y;
  const int s0 = blockIdx.x * 32, d0 = blockIdx.y * 32;
  const int z = blockIdx.z, b = z >> 2, kv = z & 3;
#pragma unroll
  for (int i = 0; i < 4; i++)
    t[ty + i * 8][tx] =
        in[((size_t)(b * S_ + s0 + ty + i * 8) * KV_ + kv) * D_ + d0 + tx];
  __syncthreads();
#pragma unroll
  for (int i = 0; i < 4; i++)
    out[((size_t)(b * KV_ + kv) * D_ + d0 + ty + i * 8) * S_ + s0 + tx] =
        t[tx][ty + i * 8];
}

// --------------------------------- NT GEMM: A (M,K) bf16, Bt (N,K) bf16, C (M,N)
// m97 structure: 128x128 tile, BK=32, global_load_lds width=16, unpadded LDS.
template <typename CT>
__global__ __launch_bounds__(256)
void gemm_nt(const u16* __restrict__ A, const u16* __restrict__ Bt,
             CT* __restrict__ C, int Md, int Nd, int Kd) {
  __shared__ u16 As[128 * 32];
  __shared__ u16 Bs[128 * 32];
  const int tid = threadIdx.x;
  const int lane = tid & 63;
  const int wave = tid >> 6;
  const int wm = wave >> 1, wn = wave & 1;
  const int li = lane & 15, quad = lane >> 4;
  const int m0 = blockIdx.y * 128;
  const int n0 = blockIdx.x * 128;

  f32x4 acc[4][4];
#pragma unroll
  for (int i = 0; i < 4; i++)
#pragma unroll
    for (int j = 0; j < 4; j++) acc[i][j] = (f32x4){0.f, 0.f, 0.f, 0.f};

  // staging: wave w stages rows [w*32, w*32+32); per instr 16 rows,
  // lane l -> row l>>2, col (l&3)*8 (16B) — matches LDS lane*16 scatter.
  const int srow = wave * 32 + (lane >> 2);
  const int scol = (lane & 3) * 8;
  const u16* Ag0 = A + (size_t)(m0 + srow) * Kd + scol;
  const u16* Ag1 = Ag0 + (size_t)16 * Kd;
  const u16* Bg0 = Bt + (size_t)(n0 + srow) * Kd + scol;
  const u16* Bg1 = Bg0 + (size_t)16 * Kd;
  u16* Al0 = &As[(wave * 32) * 32];
  u16* Al1 = &As[(wave * 32 + 16) * 32];
  u16* Bl0 = &Bs[(wave * 32) * 32];
  u16* Bl1 = &Bs[(wave * 32 + 16) * 32];

  for (int k0 = 0; k0 < Kd; k0 += 32) {
    __syncthreads();  // prev tile reads done
    gl_lds16(Ag0 + k0, Al0);
    gl_lds16(Ag1 + k0, Al1);
    gl_lds16(Bg0 + k0, Bl0);
    gl_lds16(Bg1 + k0, Bl1);
    __syncthreads();  // drains vmcnt before barrier
    bf16x8 af[4], bfr[4];
#pragma unroll
    for (int mt = 0; mt < 4; mt++)
      af[mt] = *(const bf16x8*)&As[(wm * 64 + mt * 16 + li) * 32 + quad * 8];
#pragma unroll
    for (int nt = 0; nt < 4; nt++)
      bfr[nt] = *(const bf16x8*)&Bs[(wn * 64 + nt * 16 + li) * 32 + quad * 8];
#pragma unroll
    for (int mt = 0; mt < 4; mt++)
#pragma unroll
      for (int nt = 0; nt < 4; nt++)
        acc[mt][nt] = __builtin_amdgcn_mfma_f32_16x16x32_bf16(
            af[mt], bfr[nt], acc[mt][nt], 0, 0, 0);
  }
#pragma unroll
  for (int mt = 0; mt < 4; mt++) {
    const int row = m0 + wm * 64 + mt * 16 + quad * 4;
#pragma unroll
    for (int nt = 0; nt < 4; nt++) {
      const int col = n0 + wn * 64 + nt * 16 + li;
#pragma unroll
      for (int r = 0; r < 4; r++)
        cstore(&C[(size_t)(row + r) * Nd + col], acc[mt][nt][r]);
    }
  }
}

// ------------------------ fused RMSNorm (w+1) + RoPE (+ optional score scale)
__global__ __launch_bounds__(256)
void rmsrope_kernel(const u16* __restrict__ in, const float* __restrict__ w,
                    u16* __restrict__ out, int n_heads, int tok_stride,
                    int head_stride, float scale) {
  const int warp = (blockIdx.x << 2) + (threadIdx.x >> 6);
  const int lane = threadIdx.x & 63;
  const int h = warp % n_heads;
  const int tok = warp / n_heads;
  const int s = tok & (S_ - 1);
  const int b = tok >> 11;
  const u16* src = in + (size_t)tok * tok_stride + (size_t)h * head_stride;
  float x1 = b2f(src[lane]);
  float x2 = b2f(src[lane + 64]);
  float ss = x1 * x1 + x2 * x2;
#pragma unroll
  for (int off = 1; off < 64; off <<= 1) ss += __shfl_xor(ss, off);
  const float inv = rsqrtf(ss * (1.0f / 128.0f) + 1e-6f) * scale;
  x1 *= inv * (w[lane] + 1.0f);
  x2 *= inv * (w[lane + 64] + 1.0f);
  const float invf = exp2f((float)lane * (-19.931568569324174f / 64.0f));
  const float ang = (float)s * invf;
  float sn, c;
  sincosf(ang, &sn, &c);
  const size_t ob = (((size_t)b * n_heads + h) * S_ + s) * D_;
  out[ob + lane]      = f2b(x1 * c - x2 * sn);
  out[ob + lane + 64] = f2b(x2 * c + x1 * sn);
}

// --------------------------- flash attention (transposed-S), GQA causal
// Br=128 (4 waves x 32 q as 2 n-tiles), Bc=64. S^T = K·Q^T, O^T = V^T·P^T.
// Stats reduce across quads (2 shfl); alpha/l scalar per lane.
#define KSTR 136
#define VSTR 72
#define PSTR 72
#define OSTR 136
__global__ __launch_bounds__(256)
void attn_kernel(const u16* __restrict__ Q, const u16* __restrict__ Kr,
                 const u16* __restrict__ Vt, u16* __restrict__ O) {
  __shared__ u16 lds[27136];               // 54,272 B
  u16* Ks = lds;                           // 64 x 136
  u16* Vs = lds + 64 * KSTR;               // 128 x 72
  u16* Ps = lds + 64 * KSTR + 128 * VSTR;  // 4 waves x 32 x 72
  u16* Osm = lds;                          // aliases Ks+Vs after loop (34816B)

  const int tid = threadIdx.x;
  const int lane = tid & 63;
  const int wave = tid >> 6;
  const int li = lane & 15, quad = lane >> 4;

  const int bh = blockIdx.y;
  const int b = bh >> 4, h = bh & 15;
  const int kv = h >> 2;
  const int qb = blockIdx.x * 128;
  const int qw = qb + wave * 32;

  const u16* Qb = Q + (size_t)bh * S_ * D_;
  const u16* Kb = Kr + ((size_t)b * KV_ + kv) * S_ * D_;
  const u16* Vb = Vt + ((size_t)b * KV_ + kv) * D_ * S_;

  bf16x8 qf[2][4];  // B-operand of Q^T: lane(li,quad) holds Q[qbase+li][quad*8+j]
#pragma unroll
  for (int h2 = 0; h2 < 2; h2++)
#pragma unroll
    for (int dc = 0; dc < 4; dc++)
      qf[h2][dc] = *(const bf16x8*)(Qb + (size_t)(qw + h2 * 16 + li) * D_ +
                                    dc * 32 + quad * 8);

  float m_s[2] = {-1e30f, -1e30f}, l_s[2] = {0.f, 0.f};
  f32x4 oacc[2][8];
#pragma unroll
  for (int h2 = 0; h2 < 2; h2++)
#pragma unroll
    for (int i = 0; i < 8; i++) oacc[h2][i] = (f32x4){0.f, 0.f, 0.f, 0.f};

  const int ntile = 2 * blockIdx.x + 2;
  const int kr = tid >> 2, kc = (tid & 3) * 32;
  const int vr = tid >> 1, vc = (tid & 1) * 32;
  u16* Pw = Ps + wave * 32 * PSTR;

  for (int jt = 0; jt < ntile; jt++) {
    const int j0 = jt * 64;
    __syncthreads();
    {  // stage K (64 keys x 128 d) and V^T (128 d x 64 keys)
      const u16* ksrc = Kb + (size_t)(j0 + kr) * D_ + kc;
      uint4 k0v = *(const uint4*)(ksrc);
      uint4 k1v = *(const uint4*)(ksrc + 8);
      uint4 k2v = *(const uint4*)(ksrc + 16);
      uint4 k3v = *(const uint4*)(ksrc + 24);
      const u16* vsrc = Vb + (size_t)vr * S_ + j0 + vc;
      uint4 v0v = *(const uint4*)(vsrc);
      uint4 v1v = *(const uint4*)(vsrc + 8);
      uint4 v2v = *(const uint4*)(vsrc + 16);
      uint4 v3v = *(const uint4*)(vsrc + 24);
      u16* kd = &Ks[kr * KSTR + kc];
      *(uint4*)(kd) = k0v; *(uint4*)(kd + 8) = k1v;
      *(uint4*)(kd + 16) = k2v; *(uint4*)(kd + 24) = k3v;
      u16* vd = &Vs[vr * VSTR + vc];
      *(uint4*)(vd) = v0v; *(uint4*)(vd + 8) = v1v;
      *(uint4*)(vd + 16) = v2v; *(uint4*)(vd + 24) = v3v;
    }
    __syncthreads();
    if (j0 > qw + 31) continue;  // wave-uniform; still hits loop-top barrier

    // S^T = K·Q^T : rows=keys, cols=q
    f32x4 sacc[2][4];
#pragma unroll
    for (int h2 = 0; h2 < 2; h2++)
#pragma unroll
      for (int mt = 0; mt < 4; mt++) sacc[h2][mt] = (f32x4){0.f, 0.f, 0.f, 0.f};
#pragma unroll
    for (int mt = 0; mt < 4; mt++) {
#pragma unroll
      for (int dc = 0; dc < 4; dc++) {
        bf16x8 kf = *(const bf16x8*)&Ks[(mt * 16 + li) * KSTR + dc * 32 + quad * 8];
        sacc[0][mt] = __builtin_amdgcn_mfma_f32_16x16x32_bf16(kf, qf[0][dc],
                                                              sacc[0][mt], 0, 0, 0);
        sacc[1][mt] = __builtin_amdgcn_mfma_f32_16x16x32_bf16(kf, qf[1][dc],
                                                              sacc[1][mt], 0, 0, 0);
      }
    }
    if (j0 + 63 > qw) {  // causal mask (only boundary tiles)
#pragma unroll
      for (int h2 = 0; h2 < 2; h2++) {
        const int qg = qw + h2 * 16 + li;
#pragma unroll
        for (int mt = 0; mt < 4; mt++)
#pragma unroll
          for (int r = 0; r < 4; r++)
            if (j0 + mt * 16 + quad * 4 + r > qg) sacc[h2][mt][r] = -1e30f;
      }
    }
    float alpha[2];
#pragma unroll
    for (int h2 = 0; h2 < 2; h2++) {
      float mx = -1e30f;
#pragma unroll
      for (int mt = 0; mt < 4; mt++)
#pragma unroll
        for (int r = 0; r < 4; r++) mx = fmaxf(mx, sacc[h2][mt][r]);
      mx = fmaxf(mx, __shfl_xor(mx, 16));
      mx = fmaxf(mx, __shfl_xor(mx, 32));
      const float mn = fmaxf(m_s[h2], mx);
      alpha[h2] = __expf(m_s[h2] - mn);
      m_s[h2] = mn;
      float rs = 0.f;
#pragma unroll
      for (int mt = 0; mt < 4; mt++)
#pragma unroll
        for (int r = 0; r < 4; r++) {
          float p = __expf(sacc[h2][mt][r] - mn);
          sacc[h2][mt][r] = p;
          rs += p;
        }
      rs += __shfl_xor(rs, 16);
      rs += __shfl_xor(rs, 32);
      l_s[h2] = l_s[h2] * alpha[h2] + rs;
    }
#pragma unroll
    for (int h2 = 0; h2 < 2; h2++)
#pragma unroll
      for (int mt = 0; mt < 8; mt++) {
        oacc[h2][mt][0] *= alpha[h2];
        oacc[h2][mt][1] *= alpha[h2];
        oacc[h2][mt][2] *= alpha[h2];
        oacc[h2][mt][3] *= alpha[h2];
      }
    // P^T -> wave-private LDS (rows=q, cols=keys), packed b64 writes
#pragma unroll
    for (int h2 = 0; h2 < 2; h2++)
#pragma unroll
      for (int mt = 0; mt < 4; mt++) {
        uint2 w2;
        w2.x = pk2(sacc[h2][mt][0], sacc[h2][mt][1]);
        w2.y = pk2(sacc[h2][mt][2], sacc[h2][mt][3]);
        *(uint2*)&Pw[(h2 * 16 + li) * PSTR + mt * 16 + quad * 4] = w2;
      }
    asm volatile("s_waitcnt lgkmcnt(0)" ::: "memory");  // wave-private: no barrier
    bf16x8 pf[2][2];
#pragma unroll
    for (int h2 = 0; h2 < 2; h2++)
#pragma unroll
      for (int ks = 0; ks < 2; ks++)
        pf[h2][ks] = *(const bf16x8*)&Pw[(h2 * 16 + li) * PSTR + ks * 32 + quad * 8];
    // O^T += V^T·P^T
#pragma unroll
    for (int mt = 0; mt < 8; mt++)
#pragma unroll
      for (int ks = 0; ks < 2; ks++) {
        bf16x8 vf = *(const bf16x8*)&Vs[(mt * 16 + li) * VSTR + ks * 32 + quad * 8];
        oacc[0][mt] = __builtin_amdgcn_mfma_f32_16x16x32_bf16(vf, pf[0][ks],
                                                              oacc[0][mt], 0, 0, 0);
        oacc[1][mt] = __builtin_amdgcn_mfma_f32_16x16x32_bf16(vf, pf[1][ks],
                                                              oacc[1][mt], 0, 0, 0);
      }
  }

  __syncthreads();  // all waves done with Ks/Vs before Osm alias write
  float linv[2] = {1.f / l_s[0], 1.f / l_s[1]};
#pragma unroll
  for (int h2 = 0; h2 < 2; h2++)
#pragma unroll
    for (int mt = 0; mt < 8; mt++) {
      uint2 w2;
      w2.x = pk2(oacc[h2][mt][0] * linv[h2], oacc[h2][mt][1] * linv[h2]);
      w2.y = pk2(oacc[h2][mt][2] * linv[h2], oacc[h2][mt][3] * linv[h2]);
      *(uint2*)&Osm[(wave * 32 + h2 * 16 + li) * OSTR + mt * 16 + quad * 4] = w2;
    }
  __syncthreads();
  {  // coalesced copy-out: O layout (B,S,H,D)
    const int r = tid >> 1, c0 = (tid & 1) * 64;
    u16* dst = O + (((size_t)(b * S_ + qb + r) * H_) + h) * D_ + c0;
#pragma unroll
    for (int i = 0; i < 8; i++)
      *(uint4*)(dst + i * 8) = *(const uint4*)&Osm[r * OSTR + c0 + i * 8];
  }
}

// ----------------------------------------------- sigmoid gate, x8 vectorized
__global__ __launch_bounds__(256)
void gate_kernel(const u16* __restrict__ O, const u16* __restrict__ qraw,
                 u16* __restrict__ Ag) {
  const int i = (blockIdx.x * 256 + threadIdx.x) * 8;
  const int d = i & 127;
  const int hh = (i >> 7) & 15;
  const int bs = i >> 11;
  const u16* gp = qraw + ((size_t)bs * 16 + hh) * 256 + 128 + d;
  uint4 gv = *(const uint4*)gp;
  uint4 ov = *(const uint4*)(O + i);
  const unsigned* gu = (const unsigned*)&gv;
  const unsigned* ou = (const unsigned*)&ov;
  uint4 res;
  unsigned* ru = (unsigned*)&res;
#pragma unroll
  for (int j = 0; j < 4; j++) {
    float g0 = b2f((u16)(gu[j] & 0xffff)), g1 = b2f((u16)(gu[j] >> 16));
    float o0 = b2f((u16)(ou[j] & 0xffff)), o1 = b2f((u16)(ou[j] >> 16));
    ru[j] = pk2(o0 / (1.f + __expf(-g0)), o1 / (1.f + __expf(-g1)));
  }
  *(uint4*)(Ag + i) = res;
}

extern "C" void kernel_launch(void* const* d_in, const int* in_sizes, int n_in,
                              void* d_out, int out_size, void* d_ws,
                              size_t ws_size, hipStream_t stream) {
  const float* x  = (const float*)d_in[0];
  const float* Wq = (const float*)d_in[1];
  const float* Wk = (const float*)d_in[2];
  const float* Wv = (const float*)d_in[3];
  const float* Wo = (const float*)d_in[4];
  const float* qn = (const float*)d_in[5];
  const float* kn = (const float*)d_in[6];
  float* out = (float*)d_out;
  char* ws = (char*)d_ws;

  u16* xb   = (u16*)(ws + 0);          // 16.8 MB  x bf16 (4096x2048)
  u16* Wqt  = (u16*)(ws + 16777216);   // 16.8 MB  Wq^T (4096x2048)
  u16* Wkt  = (u16*)(ws + 33554432);   //  2.1 MB  Wk^T (512x2048)
  u16* Wvt  = (u16*)(ws + 35651584);   //  2.1 MB  Wv^T (512x2048)
  u16* Wot  = (u16*)(ws + 37748736);   //  8.4 MB  Wo^T (2048x2048)
  u16* qraw = (u16*)(ws + 46137344);   // 33.6 MB  q_raw (4096x4096)
  u16* kraw = (u16*)(ws + 79691776);   //  4.2 MB  k (4096x512)
  u16* vraw = (u16*)(ws + 83886080);   //  4.2 MB  v (4096x512)
  u16* Vtb  = (u16*)(ws + 88080384);   //  4.2 MB  V^T (B,KV,D,S)
  u16* Kr   = (u16*)(ws + 92274688);   //  4.2 MB  K roped (B,KV,S,D)
  u16* Ag   = (u16*)(ws + 96468992);   // 16.8 MB  gated attn (4096x2048)
  u16* Qr = xb;    // (B,H,S,D) roped+scaled Q (aliases xb, dead after GEMMs)
  u16* Ob = Wqt;   // (B,S,H,D) attention out (aliases Wqt)

  cast_f2b_kernel<<<8192, 256, 0, stream>>>(x, xb, 4096 * 2048);
  transpose_w_kernel<<<dim3(128, 64), dim3(32, 8), 0, stream>>>(Wq, Wqt, 2048, 4096);
  transpose_w_kernel<<<dim3(16, 64), dim3(32, 8), 0, stream>>>(Wk, Wkt, 2048, 512);
  transpose_w_kernel<<<dim3(16, 64), dim3(32, 8), 0, stream>>>(Wv, Wvt, 2048, 512);
  transpose_w_kernel<<<dim3(64, 64), dim3(32, 8), 0, stream>>>(Wo, Wot, 2048, 2048);

  gemm_nt<u16><<<dim3(32, 32), 256, 0, stream>>>(xb, Wqt, qraw, 4096, 4096, 2048);
  gemm_nt<u16><<<dim3(4, 32), 256, 0, stream>>>(xb, Wkt, kraw, 4096, 512, 2048);
  gemm_nt<u16><<<dim3(4, 32), 256, 0, stream>>>(xb, Wvt, vraw, 4096, 512, 2048);

  // softmax scale folded into Q here (Q only feeds scores; gate comes from qraw)
  rmsrope_kernel<<<16384, 256, 0, stream>>>(qraw, qn, Qr, 16, 4096, 256,
                                            0.08838834764831845f);
  rmsrope_kernel<<<4096, 256, 0, stream>>>(kraw, kn, Kr, 4, 512, 128, 1.0f);
  transpose_v_kernel<<<dim3(64, 4, 8), dim3(32, 8), 0, stream>>>(vraw, Vtb);

  attn_kernel<<<dim3(16, 32), 256, 0, stream>>>(Qr, Kr, Vtb, Ob);
  gate_kernel<<<4096, 256, 0, stream>>>(Ob, qraw, Ag);
  gemm_nt<float><<<dim3(16, 32), 256, 0, stream>>>(Ag, Wot, out, 4096, 2048, 2048);
}